// Round 1
// baseline (473.711 us; speedup 1.0000x reference)
//
#include <hip/hip_runtime.h>
#include <hip/hip_bf16.h>

// GCN 2-layer: build CSR (by dst) once, reuse for both layers.
// Aggregation: 1 wave per node, lane = channel, no atomics.

#define SCAN_B 1024

__global__ __launch_bounds__(256) void k_zero(int* p, int n) {
    int i = blockIdx.x * 256 + threadIdx.x;
    if (i < n) p[i] = 0;
}

__global__ __launch_bounds__(256) void k_count(const int* __restrict__ dst, int E,
                                               int* __restrict__ cnt) {
    int i = blockIdx.x * 256 + threadIdx.x;
    if (i < E) atomicAdd(&cnt[dst[i]], 1);
}

__global__ __launch_bounds__(256) void k_dis(const int* __restrict__ cnt,
                                             float* __restrict__ dis, int N) {
    int i = blockIdx.x * 256 + threadIdx.x;
    if (i < N) dis[i] = rsqrtf((float)(cnt[i] + 1));   // +1 self loop, deg>=1
}

// exclusive scan over n elements (reads cnt[i] for i<N, else 0)
__global__ __launch_bounds__(SCAN_B) void k_scan1(const int* __restrict__ cnt, int n, int N,
                                                  int* __restrict__ off, int* __restrict__ bsums) {
    __shared__ int tmp[SCAN_B];
    int gid = blockIdx.x * SCAN_B + threadIdx.x;
    int v = (gid < N) ? cnt[gid] : 0;
    tmp[threadIdx.x] = v;
    __syncthreads();
    for (int o = 1; o < SCAN_B; o <<= 1) {
        int t = (threadIdx.x >= o) ? tmp[threadIdx.x - o] : 0;
        __syncthreads();
        tmp[threadIdx.x] += t;
        __syncthreads();
    }
    if (gid < n) off[gid] = tmp[threadIdx.x] - v;          // exclusive within block
    if (threadIdx.x == SCAN_B - 1) bsums[blockIdx.x] = tmp[SCAN_B - 1];
}

__global__ __launch_bounds__(SCAN_B) void k_scan2(int* __restrict__ bsums, int nb) {
    __shared__ int tmp[SCAN_B];
    int v = (threadIdx.x < nb) ? bsums[threadIdx.x] : 0;
    tmp[threadIdx.x] = v;
    __syncthreads();
    for (int o = 1; o < SCAN_B; o <<= 1) {
        int t = (threadIdx.x >= o) ? tmp[threadIdx.x - o] : 0;
        __syncthreads();
        tmp[threadIdx.x] += t;
        __syncthreads();
    }
    if (threadIdx.x < nb) bsums[threadIdx.x] = tmp[threadIdx.x] - v;  // exclusive
}

__global__ __launch_bounds__(256) void k_scan3(int* __restrict__ off, const int* __restrict__ bsums,
                                               int n, int* __restrict__ cursor, int N) {
    int gid = blockIdx.x * 256 + threadIdx.x;
    if (gid < n) {
        int v = off[gid] + bsums[gid >> 10];
        off[gid] = v;
        if (gid < N) cursor[gid] = v;
    }
}

__global__ __launch_bounds__(256) void k_fill(const int* __restrict__ src, const int* __restrict__ dst,
                                              int E, const float* __restrict__ dis,
                                              int* __restrict__ cursor,
                                              int* __restrict__ csr_src, float* __restrict__ csr_w) {
    int i = blockIdx.x * 256 + threadIdx.x;
    if (i >= E) return;
    int s = src[i], d = dst[i];
    int pos = atomicAdd(&cursor[d], 1);
    csr_src[pos] = s;
    csr_w[pos] = dis[s] * dis[d];
}

// B[N,64] = A[N,64] @ W[64,64]; f32 vector ALU (no fp32 MFMA on CDNA4).
// 64-row tiles; A tile in LDS with stride 68 (bank=(4r+k)%32 -> 2-way max, free).
__global__ __launch_bounds__(256) void k_gemm64(const float* __restrict__ A,
                                                const float* __restrict__ W,
                                                float* __restrict__ B, int N) {
    __shared__ float Wl[64 * 64];
    __shared__ float Al[64 * 68];
    for (int i = threadIdx.x; i < 4096; i += 256) Wl[i] = W[i];
    int tiles = (N + 63) >> 6;
    for (int tile = blockIdx.x; tile < tiles; tile += gridDim.x) {
        int row0 = tile << 6;
        __syncthreads();   // previous compute done (also covers W load first iter)
        for (int i = threadIdx.x; i < 1024; i += 256) {     // 64x64 floats as float4
            int r = i >> 4, q = i & 15;
            int gr = row0 + r;
            float4 v = (gr < N) ? ((const float4*)A)[(size_t)gr * 16 + q]
                                : make_float4(0.f, 0.f, 0.f, 0.f);
            *(float4*)&Al[r * 68 + (q << 2)] = v;
        }
        __syncthreads();
        int r  = threadIdx.x >> 2;          // 0..63
        int c0 = (threadIdx.x & 3) << 4;    // 0,16,32,48
        float acc[16];
#pragma unroll
        for (int j = 0; j < 16; j++) acc[j] = 0.f;
#pragma unroll 8
        for (int k = 0; k < 64; k++) {
            float a = Al[r * 68 + k];
#pragma unroll
            for (int j = 0; j < 16; j++) acc[j] += a * Wl[k * 64 + c0 + j];
        }
        int gr = row0 + r;
        if (gr < N) {
            float4* dp = (float4*)&B[(size_t)gr * 64 + c0];
#pragma unroll
            for (int j4 = 0; j4 < 4; j4++) dp[j4] = *(float4*)&acc[j4 * 4];
        }
    }
}

// out[n,c] = sum_{e in CSR[n]} A[src_e,c]*w_e + A[n,c]*dis[n]^2 + bias[c]; optional relu.
__global__ __launch_bounds__(256) void k_agg(const float* __restrict__ A,
                                             const int* __restrict__ off,
                                             const int* __restrict__ csr_src,
                                             const float* __restrict__ csr_w,
                                             const float* __restrict__ dis,
                                             const float* __restrict__ bias,
                                             float* __restrict__ out, int N, int relu) {
    int wave = (blockIdx.x * 256 + threadIdx.x) >> 6;
    int lane = threadIdx.x & 63;
    if (wave >= N) return;
    int n = wave;
    float d = dis[n];
    float acc = A[(size_t)n * 64 + lane] * (d * d);          // self loop
    int e = off[n], e1 = off[n + 1];
    for (; e + 1 < e1; e += 2) {                             // 2-deep for latency overlap
        int   s0 = csr_src[e],   s1 = csr_src[e + 1];
        float w0 = csr_w[e],     w1 = csr_w[e + 1];
        float a0 = A[(size_t)s0 * 64 + lane];
        float a1 = A[(size_t)s1 * 64 + lane];
        acc += a0 * w0;
        acc += a1 * w1;
    }
    if (e < e1) acc += A[(size_t)csr_src[e] * 64 + lane] * csr_w[e];
    acc += bias[lane];
    if (relu) acc = fmaxf(acc, 0.f);
    out[(size_t)n * 64 + lane] = acc;
}

extern "C" void kernel_launch(void* const* d_in, const int* in_sizes, int n_in,
                              void* d_out, int out_size, void* d_ws, size_t ws_size,
                              hipStream_t stream) {
    const float* x  = (const float*)d_in[0];
    const int*   ei = (const int*)d_in[1];
    const float* W1 = (const float*)d_in[2];
    const float* b1 = (const float*)d_in[3];
    const float* W2 = (const float*)d_in[4];
    const float* b2 = (const float*)d_in[5];
    float* outp = (float*)d_out;

    const int N = in_sizes[0] / 64;
    const int E = in_sizes[1] / 2;
    const int* src = ei;
    const int* dst = ei + E;

    // workspace carve (256B aligned)
    char* w = (char*)d_ws;
    auto carve = [&](size_t bytes) { void* p = w; w += (bytes + 255) & ~(size_t)255; return p; };
    int*   cnt     = (int*)carve((size_t)N * 4);
    int*   off     = (int*)carve((size_t)(N + 1) * 4);
    int*   cursor  = (int*)carve((size_t)N * 4);
    float* dis     = (float*)carve((size_t)N * 4);
    int*   bsums   = (int*)carve(1024 * 4);
    int*   csr_src = (int*)carve((size_t)E * 4);
    float* csr_w   = (float*)carve((size_t)E * 4);
    float* bufA    = (float*)carve((size_t)N * 64 * 4);
    (void)ws_size; (void)n_in; (void)out_size;

    const int nscan = N + 1;
    const int nb = (nscan + SCAN_B - 1) / SCAN_B;

    k_zero <<<(N + 255) / 256, 256, 0, stream>>>(cnt, N);
    k_count<<<(E + 255) / 256, 256, 0, stream>>>(dst, E, cnt);
    k_dis  <<<(N + 255) / 256, 256, 0, stream>>>(cnt, dis, N);
    k_scan1<<<nb, SCAN_B, 0, stream>>>(cnt, nscan, N, off, bsums);
    k_scan2<<<1, SCAN_B, 0, stream>>>(bsums, nb);
    k_scan3<<<(nscan + 255) / 256, 256, 0, stream>>>(off, bsums, nscan, cursor, N);
    k_fill <<<(E + 255) / 256, 256, 0, stream>>>(src, dst, E, dis, cursor, csr_src, csr_w);

    int tiles = (N + 63) >> 6;

    // layer 1: bufA = x@W1 ; d_out (temp) = agg(bufA)+b1, relu
    k_gemm64<<<tiles, 256, 0, stream>>>(x, W1, bufA, N);
    k_agg<<<(N * 64 + 255) / 256, 256, 0, stream>>>(bufA, off, csr_src, csr_w, dis, b1, outp, N, 1);

    // layer 2: bufA = h@W2 ; d_out = agg(bufA)+b2
    k_gemm64<<<tiles, 256, 0, stream>>>(outp, W2, bufA, N);
    k_agg<<<(N * 64 + 255) / 256, 256, 0, stream>>>(bufA, off, csr_src, csr_w, dis, b2, outp, N, 0);
}

// Round 2
// 418.949 us; speedup vs baseline: 1.1307x; 1.1307x over previous
//
#include <hip/hip_runtime.h>
#include <hip/hip_bf16.h>

// GCN 2-layer: build CSR (by dst) once, reuse for both layers.
// Aggregation: 1 wave per node, lane = channel, no atomics.
// R2: csr stores ONLY src (4B/edge scatter); edge weight dis[s]*dis[d]
//     computed on the fly in k_agg (dis is 400KB, L2-resident broadcast).

#define SCAN_B 1024

__global__ __launch_bounds__(256) void k_zero(int* p, int n) {
    int i = blockIdx.x * 256 + threadIdx.x;
    if (i < n) p[i] = 0;
}

__global__ __launch_bounds__(256) void k_count(const int* __restrict__ dst, int E,
                                               int* __restrict__ cnt) {
    int i = blockIdx.x * 256 + threadIdx.x;
    if (i < E) atomicAdd(&cnt[dst[i]], 1);
}

__global__ __launch_bounds__(256) void k_dis(const int* __restrict__ cnt,
                                             float* __restrict__ dis, int N) {
    int i = blockIdx.x * 256 + threadIdx.x;
    if (i < N) dis[i] = rsqrtf((float)(cnt[i] + 1));   // +1 self loop, deg>=1
}

// exclusive scan over n elements (reads cnt[i] for i<N, else 0)
__global__ __launch_bounds__(SCAN_B) void k_scan1(const int* __restrict__ cnt, int n, int N,
                                                  int* __restrict__ off, int* __restrict__ bsums) {
    __shared__ int tmp[SCAN_B];
    int gid = blockIdx.x * SCAN_B + threadIdx.x;
    int v = (gid < N) ? cnt[gid] : 0;
    tmp[threadIdx.x] = v;
    __syncthreads();
    for (int o = 1; o < SCAN_B; o <<= 1) {
        int t = (threadIdx.x >= o) ? tmp[threadIdx.x - o] : 0;
        __syncthreads();
        tmp[threadIdx.x] += t;
        __syncthreads();
    }
    if (gid < n) off[gid] = tmp[threadIdx.x] - v;          // exclusive within block
    if (threadIdx.x == SCAN_B - 1) bsums[blockIdx.x] = tmp[SCAN_B - 1];
}

__global__ __launch_bounds__(SCAN_B) void k_scan2(int* __restrict__ bsums, int nb) {
    __shared__ int tmp[SCAN_B];
    int v = (threadIdx.x < nb) ? bsums[threadIdx.x] : 0;
    tmp[threadIdx.x] = v;
    __syncthreads();
    for (int o = 1; o < SCAN_B; o <<= 1) {
        int t = (threadIdx.x >= o) ? tmp[threadIdx.x - o] : 0;
        __syncthreads();
        tmp[threadIdx.x] += t;
        __syncthreads();
    }
    if (threadIdx.x < nb) bsums[threadIdx.x] = tmp[threadIdx.x] - v;  // exclusive
}

__global__ __launch_bounds__(256) void k_scan3(int* __restrict__ off, const int* __restrict__ bsums,
                                               int n, int* __restrict__ cursor, int N) {
    int gid = blockIdx.x * 256 + threadIdx.x;
    if (gid < n) {
        int v = off[gid] + bsums[gid >> 10];
        off[gid] = v;
        if (gid < N) cursor[gid] = v;
    }
}

// one 4B random store per edge (was 2x into src+w arrays: 155MB WRITE_SIZE)
__global__ __launch_bounds__(256) void k_fill(const int* __restrict__ src, const int* __restrict__ dst,
                                              int E, int* __restrict__ cursor,
                                              int* __restrict__ csr_src) {
    int i = blockIdx.x * 256 + threadIdx.x;
    if (i >= E) return;
    int d = dst[i];
    int pos = atomicAdd(&cursor[d], 1);
    csr_src[pos] = src[i];
}

// B[N,64] = A[N,64] @ W[64,64]; f32 vector ALU (no fp32 MFMA on CDNA4).
// 64-row tiles; A tile in LDS with stride 68 (bank=(4r+k)%32 -> 2-way max, free).
__global__ __launch_bounds__(256) void k_gemm64(const float* __restrict__ A,
                                                const float* __restrict__ W,
                                                float* __restrict__ B, int N) {
    __shared__ float Wl[64 * 64];
    __shared__ float Al[64 * 68];
    for (int i = threadIdx.x; i < 4096; i += 256) Wl[i] = W[i];
    int tiles = (N + 63) >> 6;
    for (int tile = blockIdx.x; tile < tiles; tile += gridDim.x) {
        int row0 = tile << 6;
        __syncthreads();   // previous compute done (also covers W load first iter)
        for (int i = threadIdx.x; i < 1024; i += 256) {     // 64x64 floats as float4
            int r = i >> 4, q = i & 15;
            int gr = row0 + r;
            float4 v = (gr < N) ? ((const float4*)A)[(size_t)gr * 16 + q]
                                : make_float4(0.f, 0.f, 0.f, 0.f);
            *(float4*)&Al[r * 68 + (q << 2)] = v;
        }
        __syncthreads();
        int r  = threadIdx.x >> 2;          // 0..63
        int c0 = (threadIdx.x & 3) << 4;    // 0,16,32,48
        float acc[16];
#pragma unroll
        for (int j = 0; j < 16; j++) acc[j] = 0.f;
#pragma unroll 8
        for (int k = 0; k < 64; k++) {
            float a = Al[r * 68 + k];
#pragma unroll
            for (int j = 0; j < 16; j++) acc[j] += a * Wl[k * 64 + c0 + j];
        }
        int gr = row0 + r;
        if (gr < N) {
            float4* dp = (float4*)&B[(size_t)gr * 64 + c0];
#pragma unroll
            for (int j4 = 0; j4 < 4; j4++) dp[j4] = *(float4*)&acc[j4 * 4];
        }
    }
}

// out[n,c] = sum_{e in CSR[n]} A[src_e,c]*dis[src_e]*dis[n] + A[n,c]*dis[n]^2 + bias[c]
__global__ __launch_bounds__(256) void k_agg(const float* __restrict__ A,
                                             const int* __restrict__ off,
                                             const int* __restrict__ csr_src,
                                             const float* __restrict__ dis,
                                             const float* __restrict__ bias,
                                             float* __restrict__ out, int N, int relu) {
    int n = (blockIdx.x * 256 + threadIdx.x) >> 6;
    int lane = threadIdx.x & 63;
    if (n >= N) return;
    float d = dis[n];
    float acc = A[(size_t)n * 64 + lane] * (d * d);          // self loop
    int e = off[n], e1 = off[n + 1];
    for (; e + 3 < e1; e += 4) {                             // 4-deep for latency overlap
        int s0 = csr_src[e], s1 = csr_src[e + 1], s2 = csr_src[e + 2], s3 = csr_src[e + 3];
        float w0 = dis[s0], w1 = dis[s1], w2 = dis[s2], w3 = dis[s3];  // broadcast, L2-hot
        float a0 = A[(size_t)s0 * 64 + lane];
        float a1 = A[(size_t)s1 * 64 + lane];
        float a2 = A[(size_t)s2 * 64 + lane];
        float a3 = A[(size_t)s3 * 64 + lane];
        acc += a0 * (w0 * d);
        acc += a1 * (w1 * d);
        acc += a2 * (w2 * d);
        acc += a3 * (w3 * d);
    }
    for (; e < e1; ++e) {
        int s = csr_src[e];
        acc += A[(size_t)s * 64 + lane] * (dis[s] * d);
    }
    acc += bias[lane];
    if (relu) acc = fmaxf(acc, 0.f);
    out[(size_t)n * 64 + lane] = acc;
}

extern "C" void kernel_launch(void* const* d_in, const int* in_sizes, int n_in,
                              void* d_out, int out_size, void* d_ws, size_t ws_size,
                              hipStream_t stream) {
    const float* x  = (const float*)d_in[0];
    const int*   ei = (const int*)d_in[1];
    const float* W1 = (const float*)d_in[2];
    const float* b1 = (const float*)d_in[3];
    const float* W2 = (const float*)d_in[4];
    const float* b2 = (const float*)d_in[5];
    float* outp = (float*)d_out;

    const int N = in_sizes[0] / 64;
    const int E = in_sizes[1] / 2;
    const int* src = ei;
    const int* dst = ei + E;

    // workspace carve (256B aligned)
    char* w = (char*)d_ws;
    auto carve = [&](size_t bytes) { void* p = w; w += (bytes + 255) & ~(size_t)255; return p; };
    int*   cnt     = (int*)carve((size_t)N * 4);
    int*   off     = (int*)carve((size_t)(N + 1) * 4);
    int*   cursor  = (int*)carve((size_t)N * 4);
    float* dis     = (float*)carve((size_t)N * 4);
    int*   bsums   = (int*)carve(1024 * 4);
    int*   csr_src = (int*)carve((size_t)E * 4);
    float* bufA    = (float*)carve((size_t)N * 64 * 4);
    (void)ws_size; (void)n_in; (void)out_size;

    const int nscan = N + 1;
    const int nb = (nscan + SCAN_B - 1) / SCAN_B;

    k_zero <<<(N + 255) / 256, 256, 0, stream>>>(cnt, N);
    k_count<<<(E + 255) / 256, 256, 0, stream>>>(dst, E, cnt);
    k_dis  <<<(N + 255) / 256, 256, 0, stream>>>(cnt, dis, N);
    k_scan1<<<nb, SCAN_B, 0, stream>>>(cnt, nscan, N, off, bsums);
    k_scan2<<<1, SCAN_B, 0, stream>>>(bsums, nb);
    k_scan3<<<(nscan + 255) / 256, 256, 0, stream>>>(off, bsums, nscan, cursor, N);
    k_fill <<<(E + 255) / 256, 256, 0, stream>>>(src, dst, E, cursor, csr_src);

    int tiles = (N + 63) >> 6;

    // layer 1: bufA = x@W1 ; d_out (temp) = agg(bufA)+b1, relu
    k_gemm64<<<tiles, 256, 0, stream>>>(x, W1, bufA, N);
    k_agg<<<(N * 64 + 255) / 256, 256, 0, stream>>>(bufA, off, csr_src, dis, b1, outp, N, 1);

    // layer 2: bufA = h@W2 ; d_out = agg(bufA)+b2
    k_gemm64<<<tiles, 256, 0, stream>>>(outp, W2, bufA, N);
    k_agg<<<(N * 64 + 255) / 256, 256, 0, stream>>>(bufA, off, csr_src, dis, b2, outp, N, 0);
}

// Round 3
// 309.697 us; speedup vs baseline: 1.5296x; 1.3528x over previous
//
#include <hip/hip_runtime.h>
#include <hip/hip_bf16.h>

// GCN 2-layer: build CSR (by dst) once, reuse for both layers.
// R3: replace global-atomic k_count/k_fill with 2-level bucket sort:
//   bucket = dst>>10 (<=128 buckets). Chunked LDS histograms + one global
//   atomic per (chunk,bucket); per-bucket workgroups do LDS-cursor placement
//   so csr_src scatter is confined to a ~65KB L2-resident region.

#define SCAN_B 1024
#define CHUNK 4096          // 16 edges/thread * 256 threads
#define BSH 10              // nodes per bucket = 1024
#define MAXB 128            // max buckets (N <= 131072)

__global__ __launch_bounds__(256) void k_zero(int* p, int n) {
    int i = blockIdx.x * 256 + threadIdx.x;
    if (i < n) p[i] = 0;
}

// per-chunk LDS bucket histogram -> global bucket counts
__global__ __launch_bounds__(256) void k_bcount(const int* __restrict__ dst, int E,
                                                int* __restrict__ bkt_cnt) {
    __shared__ int h[MAXB];
    for (int t = threadIdx.x; t < MAXB; t += 256) h[t] = 0;
    __syncthreads();
    int chunk0 = blockIdx.x * CHUNK;
#pragma unroll
    for (int j = 0; j < 16; j++) {
        int i = chunk0 + j * 256 + threadIdx.x;
        if (i < E) atomicAdd(&h[dst[i] >> BSH], 1);
    }
    __syncthreads();
    if (threadIdx.x < MAXB && h[threadIdx.x]) atomicAdd(&bkt_cnt[threadIdx.x], h[threadIdx.x]);
}

// single-block exclusive scan of bucket counts -> bkt_off[nbkt+1], bkt_cursor
__global__ __launch_bounds__(MAXB) void k_bscan(const int* __restrict__ bkt_cnt, int nbkt,
                                                int* __restrict__ bkt_off,
                                                int* __restrict__ bkt_cursor) {
    __shared__ int tmp[MAXB];
    int v = (threadIdx.x < nbkt) ? bkt_cnt[threadIdx.x] : 0;
    tmp[threadIdx.x] = v;
    __syncthreads();
    for (int o = 1; o < MAXB; o <<= 1) {
        int t = (threadIdx.x >= o) ? tmp[threadIdx.x - o] : 0;
        __syncthreads();
        tmp[threadIdx.x] += t;
        __syncthreads();
    }
    int excl = tmp[threadIdx.x] - v;
    if (threadIdx.x < nbkt) { bkt_off[threadIdx.x] = excl; bkt_cursor[threadIdx.x] = excl; }
    if (threadIdx.x == MAXB - 1) bkt_off[nbkt] = tmp[MAXB - 1];
}

// partition edges into bucket-contiguous ebuf of packed (src,dst)
__global__ __launch_bounds__(256) void k_bscatter(const int* __restrict__ src,
                                                  const int* __restrict__ dst, int E,
                                                  int* __restrict__ bkt_cursor,
                                                  unsigned long long* __restrict__ ebuf) {
    __shared__ int hist[MAXB];
    __shared__ int base[MAXB];
    int chunk0 = blockIdx.x * CHUNK;
    for (int t = threadIdx.x; t < MAXB; t += 256) hist[t] = 0;
    __syncthreads();
    int b_[16];
#pragma unroll
    for (int j = 0; j < 16; j++) {
        int i = chunk0 + j * 256 + threadIdx.x;
        b_[j] = -1;
        if (i < E) { int b = dst[i] >> BSH; b_[j] = b; atomicAdd(&hist[b], 1); }
    }
    __syncthreads();
    if (threadIdx.x < MAXB) {
        int h = hist[threadIdx.x];
        base[threadIdx.x] = h ? atomicAdd(&bkt_cursor[threadIdx.x], h) : 0;
    }
    __syncthreads();
    for (int t = threadIdx.x; t < MAXB; t += 256) hist[t] = 0;  // reuse as rank cursor
    __syncthreads();
#pragma unroll
    for (int j = 0; j < 16; j++) {
        int i = chunk0 + j * 256 + threadIdx.x;
        if (i < E) {
            int b = b_[j];
            int rank = atomicAdd(&hist[b], 1);
            ebuf[(size_t)base[b] + rank] =
                ((unsigned long long)(unsigned)src[i] << 32) | (unsigned)dst[i];
        }
    }
}

// per-bucket workgroup: node-degree histogram in LDS -> cnt (coalesced write)
__global__ __launch_bounds__(256) void k_ncount(const unsigned long long* __restrict__ ebuf,
                                                const int* __restrict__ bkt_off, int N,
                                                int* __restrict__ cnt) {
    __shared__ int h[1 << BSH];
    int b = blockIdx.x;
    int node0 = b << BSH;
    int nn = min(1 << BSH, N - node0);
    for (int t = threadIdx.x; t < nn; t += 256) h[t] = 0;
    __syncthreads();
    int e1 = bkt_off[b + 1];
    for (int i = bkt_off[b] + threadIdx.x; i < e1; i += 256) {
        int d = (int)(ebuf[i] & 0xffffffffu);
        atomicAdd(&h[d - node0], 1);
    }
    __syncthreads();
    for (int t = threadIdx.x; t < nn; t += 256) cnt[node0 + t] = h[t];
}

__global__ __launch_bounds__(256) void k_dis(const int* __restrict__ cnt,
                                             float* __restrict__ dis, int N) {
    int i = blockIdx.x * 256 + threadIdx.x;
    if (i < N) dis[i] = rsqrtf((float)(cnt[i] + 1));   // +1 self loop
}

// exclusive scan over n elements (reads cnt[i] for i<N, else 0)
__global__ __launch_bounds__(SCAN_B) void k_scan1(const int* __restrict__ cnt, int n, int N,
                                                  int* __restrict__ off, int* __restrict__ bsums) {
    __shared__ int tmp[SCAN_B];
    int gid = blockIdx.x * SCAN_B + threadIdx.x;
    int v = (gid < N) ? cnt[gid] : 0;
    tmp[threadIdx.x] = v;
    __syncthreads();
    for (int o = 1; o < SCAN_B; o <<= 1) {
        int t = (threadIdx.x >= o) ? tmp[threadIdx.x - o] : 0;
        __syncthreads();
        tmp[threadIdx.x] += t;
        __syncthreads();
    }
    if (gid < n) off[gid] = tmp[threadIdx.x] - v;
    if (threadIdx.x == SCAN_B - 1) bsums[blockIdx.x] = tmp[SCAN_B - 1];
}

__global__ __launch_bounds__(SCAN_B) void k_scan2(int* __restrict__ bsums, int nb) {
    __shared__ int tmp[SCAN_B];
    int v = (threadIdx.x < nb) ? bsums[threadIdx.x] : 0;
    tmp[threadIdx.x] = v;
    __syncthreads();
    for (int o = 1; o < SCAN_B; o <<= 1) {
        int t = (threadIdx.x >= o) ? tmp[threadIdx.x - o] : 0;
        __syncthreads();
        tmp[threadIdx.x] += t;
        __syncthreads();
    }
    if (threadIdx.x < nb) bsums[threadIdx.x] = tmp[threadIdx.x] - v;
}

__global__ __launch_bounds__(256) void k_scan3(int* __restrict__ off, const int* __restrict__ bsums,
                                               int n) {
    int gid = blockIdx.x * 256 + threadIdx.x;
    if (gid < n) off[gid] += bsums[gid >> 10];
}

// per-bucket workgroup: place src into csr_src with LDS cursors (L2-local scatter)
__global__ __launch_bounds__(256) void k_place(const unsigned long long* __restrict__ ebuf,
                                               const int* __restrict__ bkt_off,
                                               const int* __restrict__ off, int N,
                                               int* __restrict__ csr_src) {
    __shared__ int cur[1 << BSH];
    int b = blockIdx.x;
    int node0 = b << BSH;
    int nn = min(1 << BSH, N - node0);
    for (int t = threadIdx.x; t < nn; t += 256) cur[t] = off[node0 + t];
    __syncthreads();
    int e1 = bkt_off[b + 1];
    for (int i = bkt_off[b] + threadIdx.x; i < e1; i += 256) {
        unsigned long long p = ebuf[i];
        int d = (int)(p & 0xffffffffu);
        int s = (int)(p >> 32);
        int pos = atomicAdd(&cur[d - node0], 1);
        csr_src[pos] = s;
    }
}

// B[N,64] = A[N,64] @ W[64,64]; f32 vector ALU (no fp32 MFMA on CDNA4).
__global__ __launch_bounds__(256) void k_gemm64(const float* __restrict__ A,
                                                const float* __restrict__ W,
                                                float* __restrict__ B, int N) {
    __shared__ float Wl[64 * 64];
    __shared__ float Al[64 * 68];
    for (int i = threadIdx.x; i < 4096; i += 256) Wl[i] = W[i];
    int tiles = (N + 63) >> 6;
    for (int tile = blockIdx.x; tile < tiles; tile += gridDim.x) {
        int row0 = tile << 6;
        __syncthreads();
        for (int i = threadIdx.x; i < 1024; i += 256) {
            int r = i >> 4, q = i & 15;
            int gr = row0 + r;
            float4 v = (gr < N) ? ((const float4*)A)[(size_t)gr * 16 + q]
                                : make_float4(0.f, 0.f, 0.f, 0.f);
            *(float4*)&Al[r * 68 + (q << 2)] = v;
        }
        __syncthreads();
        int r  = threadIdx.x >> 2;
        int c0 = (threadIdx.x & 3) << 4;
        float acc[16];
#pragma unroll
        for (int j = 0; j < 16; j++) acc[j] = 0.f;
#pragma unroll 8
        for (int k = 0; k < 64; k++) {
            float a = Al[r * 68 + k];
#pragma unroll
            for (int j = 0; j < 16; j++) acc[j] += a * Wl[k * 64 + c0 + j];
        }
        int gr = row0 + r;
        if (gr < N) {
            float4* dp = (float4*)&B[(size_t)gr * 64 + c0];
#pragma unroll
            for (int j4 = 0; j4 < 4; j4++) dp[j4] = *(float4*)&acc[j4 * 4];
        }
    }
}

// out[n,c] = sum_{e} A[src_e,c]*dis[src_e]*dis[n] + A[n,c]*dis[n]^2 + bias[c]
__global__ __launch_bounds__(256) void k_agg(const float* __restrict__ A,
                                             const int* __restrict__ off,
                                             const int* __restrict__ csr_src,
                                             const float* __restrict__ dis,
                                             const float* __restrict__ bias,
                                             float* __restrict__ out, int N, int relu) {
    int n = (blockIdx.x * 256 + threadIdx.x) >> 6;
    int lane = threadIdx.x & 63;
    if (n >= N) return;
    float d = dis[n];
    float acc = A[(size_t)n * 64 + lane] * (d * d);
    int e = off[n], e1 = off[n + 1];
    for (; e + 3 < e1; e += 4) {
        int s0 = csr_src[e], s1 = csr_src[e + 1], s2 = csr_src[e + 2], s3 = csr_src[e + 3];
        float w0 = dis[s0], w1 = dis[s1], w2 = dis[s2], w3 = dis[s3];
        float a0 = A[(size_t)s0 * 64 + lane];
        float a1 = A[(size_t)s1 * 64 + lane];
        float a2 = A[(size_t)s2 * 64 + lane];
        float a3 = A[(size_t)s3 * 64 + lane];
        acc += a0 * (w0 * d);
        acc += a1 * (w1 * d);
        acc += a2 * (w2 * d);
        acc += a3 * (w3 * d);
    }
    for (; e < e1; ++e) {
        int s = csr_src[e];
        acc += A[(size_t)s * 64 + lane] * (dis[s] * d);
    }
    acc += bias[lane];
    if (relu) acc = fmaxf(acc, 0.f);
    out[(size_t)n * 64 + lane] = acc;
}

extern "C" void kernel_launch(void* const* d_in, const int* in_sizes, int n_in,
                              void* d_out, int out_size, void* d_ws, size_t ws_size,
                              hipStream_t stream) {
    const float* x  = (const float*)d_in[0];
    const int*   ei = (const int*)d_in[1];
    const float* W1 = (const float*)d_in[2];
    const float* b1 = (const float*)d_in[3];
    const float* W2 = (const float*)d_in[4];
    const float* b2 = (const float*)d_in[5];
    float* outp = (float*)d_out;

    const int N = in_sizes[0] / 64;
    const int E = in_sizes[1] / 2;
    const int* src = ei;
    const int* dst = ei + E;
    const int nbkt = (N + (1 << BSH) - 1) >> BSH;   // <= MAXB

    // workspace carve (256B aligned)
    char* w = (char*)d_ws;
    auto carve = [&](size_t bytes) { void* p = w; w += (bytes + 255) & ~(size_t)255; return p; };
    int*   cnt     = (int*)carve((size_t)N * 4);
    int*   off     = (int*)carve((size_t)(N + 1) * 4);
    float* dis     = (float*)carve((size_t)N * 4);
    int*   bsums   = (int*)carve(1024 * 4);
    int*   bkt_cnt = (int*)carve(MAXB * 4);
    int*   bkt_off = (int*)carve((MAXB + 1) * 4);
    int*   bkt_cur = (int*)carve(MAXB * 4);
    int*   csr_src = (int*)carve((size_t)E * 4);
    float* bufA    = (float*)carve((size_t)N * 64 * 4);
    unsigned long long* ebuf = (unsigned long long*)bufA;  // dead before first gemm
    (void)ws_size; (void)n_in; (void)out_size;

    const int nscan = N + 1;
    const int nb = (nscan + SCAN_B - 1) / SCAN_B;
    const int nchunk = (E + CHUNK - 1) / CHUNK;

    k_zero    <<<1, 256, 0, stream>>>(bkt_cnt, MAXB);
    k_bcount  <<<nchunk, 256, 0, stream>>>(dst, E, bkt_cnt);
    k_bscan   <<<1, MAXB, 0, stream>>>(bkt_cnt, nbkt, bkt_off, bkt_cur);
    k_bscatter<<<nchunk, 256, 0, stream>>>(src, dst, E, bkt_cur, ebuf);
    k_ncount  <<<nbkt, 256, 0, stream>>>(ebuf, bkt_off, N, cnt);
    k_dis     <<<(N + 255) / 256, 256, 0, stream>>>(cnt, dis, N);
    k_scan1   <<<nb, SCAN_B, 0, stream>>>(cnt, nscan, N, off, bsums);
    k_scan2   <<<1, SCAN_B, 0, stream>>>(bsums, nb);
    k_scan3   <<<(nscan + 255) / 256, 256, 0, stream>>>(off, bsums, nscan);
    k_place   <<<nbkt, 256, 0, stream>>>(ebuf, bkt_off, off, N, csr_src);

    int tiles = (N + 63) >> 6;

    // layer 1: bufA = x@W1 ; d_out (temp) = agg(bufA)+b1, relu
    k_gemm64<<<tiles, 256, 0, stream>>>(x, W1, bufA, N);
    k_agg<<<(N * 64 + 255) / 256, 256, 0, stream>>>(bufA, off, csr_src, dis, b1, outp, N, 1);

    // layer 2: bufA = h@W2 ; d_out = agg(bufA)+b2
    k_gemm64<<<tiles, 256, 0, stream>>>(outp, W2, bufA, N);
    k_agg<<<(N * 64 + 255) / 256, 256, 0, stream>>>(bufA, off, csr_src, dis, b2, outp, N, 0);
}

// Round 4
// 288.741 us; speedup vs baseline: 1.6406x; 1.0726x over previous
//
#include <hip/hip_runtime.h>
#include <hip/hip_bf16.h>

// GCN 2-layer: build CSR (by dst) once, reuse for both layers.
// R4: gather operand stored as PRE-SCALED bf16 (Bs[s] = (A@W)[s]*dis[s]):
//   - gather row 256B -> 128B (halves k_agg FETCH)
//   - k_agg inner loop needs no weight load at all (pure sum, * dis[n] at end)

#define SCAN_B 1024
#define CHUNK 4096          // 16 edges/thread * 256 threads
#define BSH 10              // nodes per bucket = 1024
#define MAXB 128            // max buckets (N <= 131072)

__device__ __forceinline__ unsigned short f2bf(float f) {   // RNE
    unsigned u = __float_as_uint(f);
    u = (u + 0x7fff + ((u >> 16) & 1)) >> 16;
    return (unsigned short)u;
}
__device__ __forceinline__ float bf2f(unsigned short h) {
    return __uint_as_float((unsigned)h << 16);
}

__global__ __launch_bounds__(256) void k_zero(int* p, int n) {
    int i = blockIdx.x * 256 + threadIdx.x;
    if (i < n) p[i] = 0;
}

// per-chunk LDS bucket histogram -> global bucket counts
__global__ __launch_bounds__(256) void k_bcount(const int* __restrict__ dst, int E,
                                                int* __restrict__ bkt_cnt) {
    __shared__ int h[MAXB];
    for (int t = threadIdx.x; t < MAXB; t += 256) h[t] = 0;
    __syncthreads();
    int chunk0 = blockIdx.x * CHUNK;
#pragma unroll
    for (int j = 0; j < 16; j++) {
        int i = chunk0 + j * 256 + threadIdx.x;
        if (i < E) atomicAdd(&h[dst[i] >> BSH], 1);
    }
    __syncthreads();
    if (threadIdx.x < MAXB && h[threadIdx.x]) atomicAdd(&bkt_cnt[threadIdx.x], h[threadIdx.x]);
}

// single-block exclusive scan of bucket counts -> bkt_off[nbkt+1], bkt_cursor
__global__ __launch_bounds__(MAXB) void k_bscan(const int* __restrict__ bkt_cnt, int nbkt,
                                                int* __restrict__ bkt_off,
                                                int* __restrict__ bkt_cursor) {
    __shared__ int tmp[MAXB];
    int v = (threadIdx.x < nbkt) ? bkt_cnt[threadIdx.x] : 0;
    tmp[threadIdx.x] = v;
    __syncthreads();
    for (int o = 1; o < MAXB; o <<= 1) {
        int t = (threadIdx.x >= o) ? tmp[threadIdx.x - o] : 0;
        __syncthreads();
        tmp[threadIdx.x] += t;
        __syncthreads();
    }
    int excl = tmp[threadIdx.x] - v;
    if (threadIdx.x < nbkt) { bkt_off[threadIdx.x] = excl; bkt_cursor[threadIdx.x] = excl; }
    if (threadIdx.x == MAXB - 1) bkt_off[nbkt] = tmp[MAXB - 1];
}

// partition edges into bucket-contiguous ebuf of packed (src,dst)
__global__ __launch_bounds__(256) void k_bscatter(const int* __restrict__ src,
                                                  const int* __restrict__ dst, int E,
                                                  int* __restrict__ bkt_cursor,
                                                  unsigned long long* __restrict__ ebuf) {
    __shared__ int hist[MAXB];
    __shared__ int base[MAXB];
    int chunk0 = blockIdx.x * CHUNK;
    for (int t = threadIdx.x; t < MAXB; t += 256) hist[t] = 0;
    __syncthreads();
    int b_[16];
#pragma unroll
    for (int j = 0; j < 16; j++) {
        int i = chunk0 + j * 256 + threadIdx.x;
        b_[j] = -1;
        if (i < E) { int b = dst[i] >> BSH; b_[j] = b; atomicAdd(&hist[b], 1); }
    }
    __syncthreads();
    if (threadIdx.x < MAXB) {
        int h = hist[threadIdx.x];
        base[threadIdx.x] = h ? atomicAdd(&bkt_cursor[threadIdx.x], h) : 0;
    }
    __syncthreads();
    for (int t = threadIdx.x; t < MAXB; t += 256) hist[t] = 0;  // reuse as rank cursor
    __syncthreads();
#pragma unroll
    for (int j = 0; j < 16; j++) {
        int i = chunk0 + j * 256 + threadIdx.x;
        if (i < E) {
            int b = b_[j];
            int rank = atomicAdd(&hist[b], 1);
            ebuf[(size_t)base[b] + rank] =
                ((unsigned long long)(unsigned)src[i] << 32) | (unsigned)dst[i];
        }
    }
}

// per-bucket workgroup: node-degree histogram in LDS -> cnt (coalesced write)
__global__ __launch_bounds__(256) void k_ncount(const unsigned long long* __restrict__ ebuf,
                                                const int* __restrict__ bkt_off, int N,
                                                int* __restrict__ cnt) {
    __shared__ int h[1 << BSH];
    int b = blockIdx.x;
    int node0 = b << BSH;
    int nn = min(1 << BSH, N - node0);
    for (int t = threadIdx.x; t < nn; t += 256) h[t] = 0;
    __syncthreads();
    int e1 = bkt_off[b + 1];
    for (int i = bkt_off[b] + threadIdx.x; i < e1; i += 256) {
        int d = (int)(ebuf[i] & 0xffffffffu);
        atomicAdd(&h[d - node0], 1);
    }
    __syncthreads();
    for (int t = threadIdx.x; t < nn; t += 256) cnt[node0 + t] = h[t];
}

__global__ __launch_bounds__(256) void k_dis(const int* __restrict__ cnt,
                                             float* __restrict__ dis, int N) {
    int i = blockIdx.x * 256 + threadIdx.x;
    if (i < N) dis[i] = rsqrtf((float)(cnt[i] + 1));   // +1 self loop
}

// exclusive scan over n elements (reads cnt[i] for i<N, else 0)
__global__ __launch_bounds__(SCAN_B) void k_scan1(const int* __restrict__ cnt, int n, int N,
                                                  int* __restrict__ off, int* __restrict__ bsums) {
    __shared__ int tmp[SCAN_B];
    int gid = blockIdx.x * SCAN_B + threadIdx.x;
    int v = (gid < N) ? cnt[gid] : 0;
    tmp[threadIdx.x] = v;
    __syncthreads();
    for (int o = 1; o < SCAN_B; o <<= 1) {
        int t = (threadIdx.x >= o) ? tmp[threadIdx.x - o] : 0;
        __syncthreads();
        tmp[threadIdx.x] += t;
        __syncthreads();
    }
    if (gid < n) off[gid] = tmp[threadIdx.x] - v;
    if (threadIdx.x == SCAN_B - 1) bsums[blockIdx.x] = tmp[SCAN_B - 1];
}

__global__ __launch_bounds__(SCAN_B) void k_scan2(int* __restrict__ bsums, int nb) {
    __shared__ int tmp[SCAN_B];
    int v = (threadIdx.x < nb) ? bsums[threadIdx.x] : 0;
    tmp[threadIdx.x] = v;
    __syncthreads();
    for (int o = 1; o < SCAN_B; o <<= 1) {
        int t = (threadIdx.x >= o) ? tmp[threadIdx.x - o] : 0;
        __syncthreads();
        tmp[threadIdx.x] += t;
        __syncthreads();
    }
    if (threadIdx.x < nb) bsums[threadIdx.x] = tmp[threadIdx.x] - v;
}

__global__ __launch_bounds__(256) void k_scan3(int* __restrict__ off, const int* __restrict__ bsums,
                                               int n) {
    int gid = blockIdx.x * 256 + threadIdx.x;
    if (gid < n) off[gid] += bsums[gid >> 10];
}

// per-bucket workgroup: place src into csr_src with LDS cursors (L2-local scatter)
__global__ __launch_bounds__(256) void k_place(const unsigned long long* __restrict__ ebuf,
                                               const int* __restrict__ bkt_off,
                                               const int* __restrict__ off, int N,
                                               int* __restrict__ csr_src) {
    __shared__ int cur[1 << BSH];
    int b = blockIdx.x;
    int node0 = b << BSH;
    int nn = min(1 << BSH, N - node0);
    for (int t = threadIdx.x; t < nn; t += 256) cur[t] = off[node0 + t];
    __syncthreads();
    int e1 = bkt_off[b + 1];
    for (int i = bkt_off[b] + threadIdx.x; i < e1; i += 256) {
        unsigned long long p = ebuf[i];
        int d = (int)(p & 0xffffffffu);
        int s = (int)(p >> 32);
        int pos = atomicAdd(&cur[d - node0], 1);
        csr_src[pos] = s;
    }
}

// Bs[N,64](bf16) = (A[N,64] @ W[64,64]) * dis[row]; f32 vector ALU.
__global__ __launch_bounds__(256) void k_gemm64s(const float* __restrict__ A,
                                                 const float* __restrict__ W,
                                                 const float* __restrict__ dis,
                                                 unsigned short* __restrict__ Bs, int N) {
    __shared__ float Wl[64 * 64];
    __shared__ float Al[64 * 68];
    for (int i = threadIdx.x; i < 4096; i += 256) Wl[i] = W[i];
    int tiles = (N + 63) >> 6;
    for (int tile = blockIdx.x; tile < tiles; tile += gridDim.x) {
        int row0 = tile << 6;
        __syncthreads();
        for (int i = threadIdx.x; i < 1024; i += 256) {
            int r = i >> 4, q = i & 15;
            int gr = row0 + r;
            float4 v = (gr < N) ? ((const float4*)A)[(size_t)gr * 16 + q]
                                : make_float4(0.f, 0.f, 0.f, 0.f);
            *(float4*)&Al[r * 68 + (q << 2)] = v;
        }
        __syncthreads();
        int r  = threadIdx.x >> 2;
        int c0 = (threadIdx.x & 3) << 4;
        float acc[16];
#pragma unroll
        for (int j = 0; j < 16; j++) acc[j] = 0.f;
#pragma unroll 8
        for (int k = 0; k < 64; k++) {
            float a = Al[r * 68 + k];
#pragma unroll
            for (int j = 0; j < 16; j++) acc[j] += a * Wl[k * 64 + c0 + j];
        }
        int gr = row0 + r;
        if (gr < N) {
            float d = dis[gr];
            uint4 pk[2];
            unsigned* pw = (unsigned*)pk;
#pragma unroll
            for (int j = 0; j < 8; j++) {
                unsigned lo = f2bf(acc[2 * j] * d);
                unsigned hi = f2bf(acc[2 * j + 1] * d);
                pw[j] = lo | (hi << 16);
            }
            uint4* dp = (uint4*)&Bs[(size_t)gr * 64 + c0];
            dp[0] = pk[0];
            dp[1] = pk[1];
        }
    }
}

// out[n,c] = ( sum_{e} Bs[src_e,c] + Bs[n,c] ) * dis[n] + bias[c]   (Bs pre-scaled bf16)
__global__ __launch_bounds__(256) void k_agg(const unsigned short* __restrict__ Bs,
                                             const int* __restrict__ off,
                                             const int* __restrict__ csr_src,
                                             const float* __restrict__ dis,
                                             const float* __restrict__ bias,
                                             float* __restrict__ out, int N, int relu) {
    int n = (blockIdx.x * 256 + threadIdx.x) >> 6;
    int lane = threadIdx.x & 63;
    if (n >= N) return;
    float acc = bf2f(Bs[(size_t)n * 64 + lane]);     // self loop (pre-scaled)
    int e = off[n], e1 = off[n + 1];
    for (; e + 3 < e1; e += 4) {
        int s0 = csr_src[e], s1 = csr_src[e + 1], s2 = csr_src[e + 2], s3 = csr_src[e + 3];
        float a0 = bf2f(Bs[(size_t)s0 * 64 + lane]);
        float a1 = bf2f(Bs[(size_t)s1 * 64 + lane]);
        float a2 = bf2f(Bs[(size_t)s2 * 64 + lane]);
        float a3 = bf2f(Bs[(size_t)s3 * 64 + lane]);
        acc += a0 + a1 + a2 + a3;
    }
    for (; e < e1; ++e)
        acc += bf2f(Bs[(size_t)csr_src[e] * 64 + lane]);
    acc = acc * dis[n] + bias[lane];
    if (relu) acc = fmaxf(acc, 0.f);
    out[(size_t)n * 64 + lane] = acc;
}

extern "C" void kernel_launch(void* const* d_in, const int* in_sizes, int n_in,
                              void* d_out, int out_size, void* d_ws, size_t ws_size,
                              hipStream_t stream) {
    const float* x  = (const float*)d_in[0];
    const int*   ei = (const int*)d_in[1];
    const float* W1 = (const float*)d_in[2];
    const float* b1 = (const float*)d_in[3];
    const float* W2 = (const float*)d_in[4];
    const float* b2 = (const float*)d_in[5];
    float* outp = (float*)d_out;

    const int N = in_sizes[0] / 64;
    const int E = in_sizes[1] / 2;
    const int* src = ei;
    const int* dst = ei + E;
    const int nbkt = (N + (1 << BSH) - 1) >> BSH;   // <= MAXB

    // workspace carve (256B aligned)
    char* w = (char*)d_ws;
    auto carve = [&](size_t bytes) { void* p = w; w += (bytes + 255) & ~(size_t)255; return p; };
    int*   cnt     = (int*)carve((size_t)N * 4);
    int*   off     = (int*)carve((size_t)(N + 1) * 4);
    float* dis     = (float*)carve((size_t)N * 4);
    int*   bsums   = (int*)carve(1024 * 4);
    int*   bkt_cnt = (int*)carve(MAXB * 4);
    int*   bkt_off = (int*)carve((MAXB + 1) * 4);
    int*   bkt_cur = (int*)carve(MAXB * 4);
    int*   csr_src = (int*)carve((size_t)E * 4);
    unsigned short* bufS = (unsigned short*)carve((size_t)N * 64 * 2);  // scaled bf16
    unsigned long long* ebuf = (unsigned long long*)carve((size_t)E * 8);
    (void)ws_size; (void)n_in; (void)out_size;

    const int nscan = N + 1;
    const int nb = (nscan + SCAN_B - 1) / SCAN_B;
    const int nchunk = (E + CHUNK - 1) / CHUNK;

    k_zero    <<<1, 256, 0, stream>>>(bkt_cnt, MAXB);
    k_bcount  <<<nchunk, 256, 0, stream>>>(dst, E, bkt_cnt);
    k_bscan   <<<1, MAXB, 0, stream>>>(bkt_cnt, nbkt, bkt_off, bkt_cur);
    k_bscatter<<<nchunk, 256, 0, stream>>>(src, dst, E, bkt_cur, ebuf);
    k_ncount  <<<nbkt, 256, 0, stream>>>(ebuf, bkt_off, N, cnt);
    k_dis     <<<(N + 255) / 256, 256, 0, stream>>>(cnt, dis, N);
    k_scan1   <<<nb, SCAN_B, 0, stream>>>(cnt, nscan, N, off, bsums);
    k_scan2   <<<1, SCAN_B, 0, stream>>>(bsums, nb);
    k_scan3   <<<(nscan + 255) / 256, 256, 0, stream>>>(off, bsums, nscan);
    k_place   <<<nbkt, 256, 0, stream>>>(ebuf, bkt_off, off, N, csr_src);

    int tiles = (N + 63) >> 6;

    // layer 1: bufS = (x@W1)*dis (bf16) ; h(outp temp) = agg(bufS)*dis + b1, relu
    k_gemm64s<<<tiles, 256, 0, stream>>>(x, W1, dis, bufS, N);
    k_agg<<<(N * 64 + 255) / 256, 256, 0, stream>>>(bufS, off, csr_src, dis, b1, outp, N, 1);

    // layer 2: bufS = (h@W2)*dis (bf16) ; out = agg(bufS)*dis + b2
    k_gemm64s<<<tiles, 256, 0, stream>>>(outp, W2, dis, bufS, N);
    k_agg<<<(N * 64 + 255) / 256, 256, 0, stream>>>(bufS, off, csr_src, dis, b2, outp, N, 0);
}